// Round 1
// baseline (1419.647 us; speedup 1.0000x reference)
//
#include <hip/hip_runtime.h>

static constexpr int DM = 1024;   // d_model
static constexpr int NH = 16;     // heads
static constexpr int DK = 64;     // head dim
static constexpr int S  = 2048;   // seq len
static constexpr int B  = 2;      // batch
static constexpr float LOG2E = 1.4426950408889634f;

// ---------------------------------------------------------------------------
// GEMM: Y = X @ W^T + bias.  X:(M,1024) row-major, W:(N,1024) row-major.
// BM=BN=128, BK=16, 256 threads, 8x8 micro-tile per thread.
// SCATTER=true  -> write Y[m, n] into (B,H,S,DK) layout (QKV projections)
// SCATTER=false -> write Y row-major (output projection)
// ---------------------------------------------------------------------------
template<bool SCATTER>
__global__ __launch_bounds__(256) void gemm_xwT(const float* __restrict__ X,
                                                const float* __restrict__ W,
                                                const float* __restrict__ bias,
                                                float* __restrict__ out)
{
    __shared__ float Xs[16][132];   // [k][m], +4 pad keeps float4 alignment
    __shared__ float Ws[16][132];   // [k][n]

    const int t  = threadIdx.x;
    const int tx = t & 15;
    const int ty = t >> 4;
    const int m0 = blockIdx.y * 128;
    const int n0 = blockIdx.x * 128;

    float acc[8][8];
#pragma unroll
    for (int i = 0; i < 8; ++i)
#pragma unroll
        for (int j = 0; j < 8; ++j) acc[i][j] = 0.f;

    const int c4 = (t & 3) * 4;   // k offset of this thread's float4
    const int r  = t >> 2;        // 0..63 (row within tile, two passes)

    for (int k0 = 0; k0 < DM; k0 += 16) {
        // global loads (coalesced float4 along k)
        float4 xa = *(const float4*)&X[(size_t)(m0 + r)      * DM + k0 + c4];
        float4 xb = *(const float4*)&X[(size_t)(m0 + r + 64) * DM + k0 + c4];
        float4 wa = *(const float4*)&W[(size_t)(n0 + r)      * DM + k0 + c4];
        float4 wb = *(const float4*)&W[(size_t)(n0 + r + 64) * DM + k0 + c4];
        __syncthreads();   // previous compute done before overwrite
        Xs[c4+0][r]    = xa.x; Xs[c4+1][r]    = xa.y; Xs[c4+2][r]    = xa.z; Xs[c4+3][r]    = xa.w;
        Xs[c4+0][r+64] = xb.x; Xs[c4+1][r+64] = xb.y; Xs[c4+2][r+64] = xb.z; Xs[c4+3][r+64] = xb.w;
        Ws[c4+0][r]    = wa.x; Ws[c4+1][r]    = wa.y; Ws[c4+2][r]    = wa.z; Ws[c4+3][r]    = wa.w;
        Ws[c4+0][r+64] = wb.x; Ws[c4+1][r+64] = wb.y; Ws[c4+2][r+64] = wb.z; Ws[c4+3][r+64] = wb.w;
        __syncthreads();

#pragma unroll
        for (int kk = 0; kk < 16; ++kk) {
            float a[8], bb[8];
            *(float4*)&a[0]  = *(const float4*)&Xs[kk][ty*8];
            *(float4*)&a[4]  = *(const float4*)&Xs[kk][ty*8+4];
            *(float4*)&bb[0] = *(const float4*)&Ws[kk][tx*8];
            *(float4*)&bb[4] = *(const float4*)&Ws[kk][tx*8+4];
#pragma unroll
            for (int i = 0; i < 8; ++i)
#pragma unroll
                for (int j = 0; j < 8; ++j)
                    acc[i][j] = fmaf(a[i], bb[j], acc[i][j]);
        }
    }

    // epilogue: bias + store (float4 blocks of 4 consecutive n never cross a head)
#pragma unroll
    for (int i = 0; i < 8; ++i) {
        const int m = m0 + ty*8 + i;
#pragma unroll
        for (int j4 = 0; j4 < 8; j4 += 4) {
            const int n = n0 + tx*8 + j4;
            float4 v = make_float4(acc[i][j4+0] + bias[n+0],
                                   acc[i][j4+1] + bias[n+1],
                                   acc[i][j4+2] + bias[n+2],
                                   acc[i][j4+3] + bias[n+3]);
            if (SCATTER) {
                const int bb2 = m >> 11;      // m / 2048
                const int ss  = m & (S - 1);
                const int h   = n >> 6;
                const int dk  = n & (DK - 1);
                *(float4*)&out[((size_t)((bb2*NH + h)*S + ss))*DK + dk] = v;
            } else {
                *(float4*)&out[(size_t)m * DM + n] = v;
            }
        }
    }
}

// ---------------------------------------------------------------------------
// Flash-style attention. 1 block = (b, h, 64 q-rows). 256 threads (16x16).
// Online softmax in exp2 domain: Q pre-scaled by log2e/8, bias by log2e.
// P reuses the K LDS buffer (scores consumed before P write).
// ---------------------------------------------------------------------------
__global__ __launch_bounds__(256) void attn_kernel(const float* __restrict__ Q,
                                                   const float* __restrict__ K,
                                                   const float* __restrict__ V,
                                                   const float* __restrict__ relb,
                                                   float* __restrict__ aout)
{
    __shared__ float Qs[64][68];
    __shared__ float KPs[64][68];   // K tile, then P tile
    __shared__ float Vs[64][68];
    __shared__ float rb[257];

    const int t  = threadIdx.x;
    const int tx = t & 15;
    const int ty = t >> 4;
    const int q0 = blockIdx.x * 64;
    const int h  = blockIdx.y;
    const int b  = blockIdx.z;

    const float* Qb = Q + (size_t)((b*NH + h) * S) * DK;
    const float* Kb = K + (size_t)((b*NH + h) * S) * DK;
    const float* Vb = V + (size_t)((b*NH + h) * S) * DK;

    for (int i = t; i < 257; i += 256) rb[i] = relb[h*257 + i] * LOG2E;

    {
        const int dk4 = (t & 15) * 4;
        const int r0  = t >> 4;
        const float sc = LOG2E * 0.125f;   // log2e / sqrt(64)
#pragma unroll
        for (int rr = 0; rr < 64; rr += 16) {
            float4 v = *(const float4*)&Qb[(size_t)(q0 + r0 + rr) * DK + dk4];
            v.x *= sc; v.y *= sc; v.z *= sc; v.w *= sc;
            *(float4*)&Qs[r0 + rr][dk4] = v;
        }
    }

    float m_run[4], l_run[4], o[4][4];
#pragma unroll
    for (int i = 0; i < 4; ++i) {
        m_run[i] = -1e30f; l_run[i] = 0.f;
#pragma unroll
        for (int j = 0; j < 4; ++j) o[i][j] = 0.f;
    }

    __syncthreads();   // Qs, rb ready

    for (int kt = 0; kt < S/64; ++kt) {
        const int k0  = kt * 64;
        const int dk4 = (t & 15) * 4;
        const int r0  = t >> 4;

        // prefetch K/V tiles to registers (no LDS touch yet)
        float4 kreg[4], vreg[4];
#pragma unroll
        for (int rr = 0; rr < 4; ++rr) {
            kreg[rr] = *(const float4*)&Kb[(size_t)(k0 + r0 + rr*16) * DK + dk4];
            vreg[rr] = *(const float4*)&Vb[(size_t)(k0 + r0 + rr*16) * DK + dk4];
        }
        __syncthreads();   // previous tile (P, V) fully consumed
#pragma unroll
        for (int rr = 0; rr < 4; ++rr) {
            *(float4*)&KPs[r0 + rr*16][dk4] = kreg[rr];
            *(float4*)&Vs[r0 + rr*16][dk4]  = vreg[rr];
        }
        __syncthreads();

        // scores: s[i][j] = Qs[ty*4+i] . KPs[tx*4+j]   (exp2 domain, pre-scaled)
        float s4[4][4];
#pragma unroll
        for (int i = 0; i < 4; ++i)
#pragma unroll
            for (int j = 0; j < 4; ++j) s4[i][j] = 0.f;
#pragma unroll
        for (int kk = 0; kk < 64; kk += 4) {
            float4 a[4], bv[4];
#pragma unroll
            for (int i = 0; i < 4; ++i) a[i]  = *(const float4*)&Qs[ty*4+i][kk];
#pragma unroll
            for (int j = 0; j < 4; ++j) bv[j] = *(const float4*)&KPs[tx*4+j][kk];
#pragma unroll
            for (int i = 0; i < 4; ++i)
#pragma unroll
                for (int j = 0; j < 4; ++j)
                    s4[i][j] += a[i].x*bv[j].x + a[i].y*bv[j].y
                              + a[i].z*bv[j].z + a[i].w*bv[j].w;
        }

        // relative bias + row max
        float tm[4];
#pragma unroll
        for (int i = 0; i < 4; ++i) {
            const int qg = q0 + ty*4 + i;
            tm[i] = -1e30f;
#pragma unroll
            for (int j = 0; j < 4; ++j) {
                const int kg  = k0 + tx*4 + j;
                int rel = qg - kg;
                rel = rel < -128 ? -128 : (rel > 128 ? 128 : rel);
                s4[i][j] += rb[rel + 128];
                tm[i] = fmaxf(tm[i], s4[i][j]);
            }
#pragma unroll
            for (int off = 1; off < 16; off <<= 1)
                tm[i] = fmaxf(tm[i], __shfl_xor(tm[i], off));
        }

        // online softmax update (all 16 tx lanes hold identical row stats)
        float alpha[4];
#pragma unroll
        for (int i = 0; i < 4; ++i) {
            const float mn = fmaxf(m_run[i], tm[i]);
            alpha[i] = exp2f(m_run[i] - mn);
            m_run[i] = mn;
            float rs = 0.f;
#pragma unroll
            for (int j = 0; j < 4; ++j) {
                s4[i][j] = exp2f(s4[i][j] - mn);
                rs += s4[i][j];
            }
#pragma unroll
            for (int off = 1; off < 16; off <<= 1)
                rs += __shfl_xor(rs, off);
            l_run[i] = l_run[i]*alpha[i] + rs;
        }

        __syncthreads();   // everyone done reading K from KPs
#pragma unroll
        for (int i = 0; i < 4; ++i)
            *(float4*)&KPs[ty*4+i][tx*4] = make_float4(s4[i][0], s4[i][1], s4[i][2], s4[i][3]);
        __syncthreads();

        // PV: o[i][j] = o[i][j]*alpha + sum_k P[q][k] * V[k][d]
#pragma unroll
        for (int i = 0; i < 4; ++i)
#pragma unroll
            for (int j = 0; j < 4; ++j) o[i][j] *= alpha[i];

#pragma unroll
        for (int kk = 0; kk < 64; kk += 4) {
            float4 p[4];
#pragma unroll
            for (int i = 0; i < 4; ++i) p[i] = *(const float4*)&KPs[ty*4+i][kk];
            const float4 v0 = *(const float4*)&Vs[kk+0][tx*4];
            const float4 v1 = *(const float4*)&Vs[kk+1][tx*4];
            const float4 v2 = *(const float4*)&Vs[kk+2][tx*4];
            const float4 v3 = *(const float4*)&Vs[kk+3][tx*4];
#pragma unroll
            for (int i = 0; i < 4; ++i) {
                o[i][0] = fmaf(p[i].x, v0.x, o[i][0]);
                o[i][1] = fmaf(p[i].x, v0.y, o[i][1]);
                o[i][2] = fmaf(p[i].x, v0.z, o[i][2]);
                o[i][3] = fmaf(p[i].x, v0.w, o[i][3]);
                o[i][0] = fmaf(p[i].y, v1.x, o[i][0]);
                o[i][1] = fmaf(p[i].y, v1.y, o[i][1]);
                o[i][2] = fmaf(p[i].y, v1.z, o[i][2]);
                o[i][3] = fmaf(p[i].y, v1.w, o[i][3]);
                o[i][0] = fmaf(p[i].z, v2.x, o[i][0]);
                o[i][1] = fmaf(p[i].z, v2.y, o[i][1]);
                o[i][2] = fmaf(p[i].z, v2.z, o[i][2]);
                o[i][3] = fmaf(p[i].z, v2.w, o[i][3]);
                o[i][0] = fmaf(p[i].w, v3.x, o[i][0]);
                o[i][1] = fmaf(p[i].w, v3.y, o[i][1]);
                o[i][2] = fmaf(p[i].w, v3.z, o[i][2]);
                o[i][3] = fmaf(p[i].w, v3.w, o[i][3]);
            }
        }
    }

    // epilogue: normalize, write (b, s, h*64+d) row-major
#pragma unroll
    for (int i = 0; i < 4; ++i) {
        const float inv = 1.0f / l_run[i];
        const int sg = q0 + ty*4 + i;
        float4 v = make_float4(o[i][0]*inv, o[i][1]*inv, o[i][2]*inv, o[i][3]*inv);
        *(float4*)&aout[(size_t)(b*S + sg) * DM + h*DK + tx*4] = v;
    }
}

// ---------------------------------------------------------------------------
extern "C" void kernel_launch(void* const* d_in, const int* in_sizes, int n_in,
                              void* d_out, int out_size, void* d_ws, size_t ws_size,
                              hipStream_t stream)
{
    const float* x    = (const float*)d_in[0];
    const float* Wq   = (const float*)d_in[1];
    const float* bq   = (const float*)d_in[2];
    const float* Wk   = (const float*)d_in[3];
    const float* bk   = (const float*)d_in[4];
    const float* Wv   = (const float*)d_in[5];
    const float* bv   = (const float*)d_in[6];
    const float* Wo   = (const float*)d_in[7];
    const float* bo   = (const float*)d_in[8];
    const float* relb = (const float*)d_in[9];

    float* ws = (float*)d_ws;
    const size_t NQ = (size_t)B * NH * S * DK;   // 4,194,304 elements each
    float* Qw = ws;
    float* Kw = Qw + NQ;
    float* Vw = Kw + NQ;
    float* AO = Vw + NQ;                          // attention output (B,S,DM)

    dim3 gg(DM/128, (B*S)/128);                   // (8, 32)
    gemm_xwT<true ><<<gg, 256, 0, stream>>>(x,  Wq, bq, Qw);
    gemm_xwT<true ><<<gg, 256, 0, stream>>>(x,  Wk, bk, Kw);
    gemm_xwT<true ><<<gg, 256, 0, stream>>>(x,  Wv, bv, Vw);
    attn_kernel<<<dim3(S/64, NH, B), 256, 0, stream>>>(Qw, Kw, Vw, relb, AO);
    gemm_xwT<false><<<gg, 256, 0, stream>>>(AO, Wo, bo, (float*)d_out);
}

// Round 2
// 709.459 us; speedup vs baseline: 2.0010x; 2.0010x over previous
//
#include <hip/hip_runtime.h>

static constexpr int DM = 1024;   // d_model
static constexpr int NH = 16;     // heads
static constexpr int DK = 64;     // head dim
static constexpr int S  = 2048;   // seq len
static constexpr int B  = 2;      // batch
static constexpr float LOG2E = 1.4426950408889634f;

typedef _Float16 f16;
typedef _Float16 f16x8 __attribute__((ext_vector_type(8)));
typedef _Float16 f16x4 __attribute__((ext_vector_type(4)));
typedef float    f32x4 __attribute__((ext_vector_type(4)));

// ---------------------------------------------------------------------------
// GEMM: Y = X @ W^T + bias.  X:(M,1024) row-major, W:(N,1024) row-major.
// BM=BN=128, BK=16, 256 threads, 8x8 micro-tile per thread.
// HS=true  -> write f16 (pre-scaled) into (B,H,S,DK) layout (QKV projections)
// HS=false -> write f32 row-major (output projection)
// ---------------------------------------------------------------------------
template<bool HS>
__global__ __launch_bounds__(256) void gemm_xwT(const float* __restrict__ X,
                                                const float* __restrict__ W,
                                                const float* __restrict__ bias,
                                                void* __restrict__ outv,
                                                float scale)
{
    __shared__ float Xs[16][132];
    __shared__ float Ws[16][132];

    const int t  = threadIdx.x;
    const int tx = t & 15;
    const int ty = t >> 4;
    const int m0 = blockIdx.y * 128;
    const int n0 = blockIdx.x * 128;

    float acc[8][8];
#pragma unroll
    for (int i = 0; i < 8; ++i)
#pragma unroll
        for (int j = 0; j < 8; ++j) acc[i][j] = 0.f;

    const int c4 = (t & 3) * 4;
    const int r  = t >> 2;

    for (int k0 = 0; k0 < DM; k0 += 16) {
        float4 xa = *(const float4*)&X[(size_t)(m0 + r)      * DM + k0 + c4];
        float4 xb = *(const float4*)&X[(size_t)(m0 + r + 64) * DM + k0 + c4];
        float4 wa = *(const float4*)&W[(size_t)(n0 + r)      * DM + k0 + c4];
        float4 wb = *(const float4*)&W[(size_t)(n0 + r + 64) * DM + k0 + c4];
        __syncthreads();
        Xs[c4+0][r]    = xa.x; Xs[c4+1][r]    = xa.y; Xs[c4+2][r]    = xa.z; Xs[c4+3][r]    = xa.w;
        Xs[c4+0][r+64] = xb.x; Xs[c4+1][r+64] = xb.y; Xs[c4+2][r+64] = xb.z; Xs[c4+3][r+64] = xb.w;
        Ws[c4+0][r]    = wa.x; Ws[c4+1][r]    = wa.y; Ws[c4+2][r]    = wa.z; Ws[c4+3][r]    = wa.w;
        Ws[c4+0][r+64] = wb.x; Ws[c4+1][r+64] = wb.y; Ws[c4+2][r+64] = wb.z; Ws[c4+3][r+64] = wb.w;
        __syncthreads();

#pragma unroll
        for (int kk = 0; kk < 16; ++kk) {
            float a[8], bb[8];
            *(float4*)&a[0]  = *(const float4*)&Xs[kk][ty*8];
            *(float4*)&a[4]  = *(const float4*)&Xs[kk][ty*8+4];
            *(float4*)&bb[0] = *(const float4*)&Ws[kk][tx*8];
            *(float4*)&bb[4] = *(const float4*)&Ws[kk][tx*8+4];
#pragma unroll
            for (int i = 0; i < 8; ++i)
#pragma unroll
                for (int j = 0; j < 8; ++j)
                    acc[i][j] = fmaf(a[i], bb[j], acc[i][j]);
        }
    }

#pragma unroll
    for (int i = 0; i < 8; ++i) {
        const int m = m0 + ty*8 + i;
#pragma unroll
        for (int j4 = 0; j4 < 8; j4 += 4) {
            const int n = n0 + tx*8 + j4;
            float4 v = make_float4((acc[i][j4+0] + bias[n+0]) * scale,
                                   (acc[i][j4+1] + bias[n+1]) * scale,
                                   (acc[i][j4+2] + bias[n+2]) * scale,
                                   (acc[i][j4+3] + bias[n+3]) * scale);
            if (HS) {
                const int bb2 = m >> 11;
                const int ss  = m & (S - 1);
                const int h   = n >> 6;
                const int dk  = n & (DK - 1);
                f16x4 hv = { (f16)v.x, (f16)v.y, (f16)v.z, (f16)v.w };
                *(f16x4*)&((f16*)outv)[((size_t)((bb2*NH + h)*S + ss))*DK + dk] = hv;
            } else {
                *(float4*)&((float*)outv)[(size_t)m * DM + n] = v;
            }
        }
    }
}

// ---------------------------------------------------------------------------
// Flash attention, f16 MFMA core (fp32 accumulate).
// Block = 128 q-rows of one (b,h); 256 threads = 4 waves, 32 q-rows/wave.
// K-tiles of 64. mfma_f32_16x16x32_f16.
//   QK: A=Q[m=q][k=d] from Qs, B=K[n=seq][k=d] from Ks  -> S C-layout (row=q,col=seq)
//   PV: A=P[m=q][k=seq] from Ps, B=V^T[n=d][k=seq] from Vt -> O C-layout (row=q,col=d)
// O and S share row=q layout so softmax stats never leave registers.
// LDS strides 72 halves: all b128 frag reads at the 8-clk floor (<=2-way alias).
// ---------------------------------------------------------------------------
__global__ __launch_bounds__(256) void attn_f16(const f16* __restrict__ Q,
                                                const f16* __restrict__ K,
                                                const f16* __restrict__ V,
                                                const float* __restrict__ relb,
                                                float* __restrict__ aout)
{
    __shared__ f16 Qs[128*72];
    __shared__ f16 Ks[64*72];
    __shared__ f16 Vt[64*72];     // transposed: Vt[d][seq]
    __shared__ f16 Ps[128*72];    // per-wave 32-row slabs
    __shared__ float rb[257];

    const int t    = threadIdx.x;
    const int w    = t >> 6;        // wave 0..3
    const int lane = t & 63;
    const int tx   = lane & 15;
    const int quad = lane >> 4;     // 0..3
    const int q0   = blockIdx.x * 128;
    const int h    = blockIdx.y;
    const int b    = blockIdx.z;

    const f16* Qb = Q + (size_t)((b*NH + h) * S) * DK;
    const f16* Kb = K + (size_t)((b*NH + h) * S) * DK;
    const f16* Vb = V + (size_t)((b*NH + h) * S) * DK;

    for (int i = t; i < 257; i += 256) rb[i] = relb[h*257 + i] * LOG2E;

    {   // stage Q once (already f16, pre-scaled by log2e/8 in GEMM epilogue)
        const int row = t >> 1;
        const int ch  = (t & 1) * 32;
        const f16* src = Qb + (size_t)(q0 + row) * DK + ch;
#pragma unroll
        for (int j = 0; j < 4; ++j)
            *(f16x8*)&Qs[row*72 + ch + j*8] = *(const f16x8*)(src + j*8);
    }

    f32x4 co[2][4];                 // O accum [mt][nt], C-layout
    float m_run[2][4], l_run[2][4];
#pragma unroll
    for (int mt = 0; mt < 2; ++mt)
#pragma unroll
        for (int r = 0; r < 4; ++r) { m_run[mt][r] = -1e30f; l_run[mt][r] = 0.f; }
#pragma unroll
    for (int mt = 0; mt < 2; ++mt)
#pragma unroll
        for (int nt = 0; nt < 4; ++nt) co[mt][nt] = (f32x4){0.f, 0.f, 0.f, 0.f};

    for (int kt = 0; kt < S/64; ++kt) {
        const int k0 = kt * 64;

        // ---- global prefetch to regs ----
        const int seq = t & 63, d0k = (t >> 6) * 16;          // K: wave w covers d [16w,16w+16)
        f16x8 kr0 = *(const f16x8*)(Kb + (size_t)(k0 + seq)*DK + d0k);
        f16x8 kr1 = *(const f16x8*)(Kb + (size_t)(k0 + seq)*DK + d0k + 8);
        const int s2 = (t & 31) * 2, d0v = (t >> 5) * 8;      // V: row pairs for transpose pack
        f16x8 vr0 = *(const f16x8*)(Vb + (size_t)(k0 + s2    )*DK + d0v);
        f16x8 vr1 = *(const f16x8*)(Vb + (size_t)(k0 + s2 + 1)*DK + d0v);

        __syncthreads();   // previous tile's Ks/Vt reads complete
        *(f16x8*)&Ks[seq*72 + d0k    ] = kr0;
        *(f16x8*)&Ks[seq*72 + d0k + 8] = kr1;
        {   // V transpose: pack (seq s2, s2+1) halves per d into one dword
            const unsigned short* u0 = (const unsigned short*)&vr0;
            const unsigned short* u1 = (const unsigned short*)&vr1;
#pragma unroll
            for (int j = 0; j < 8; ++j) {
                unsigned int pw = (unsigned int)u0[j] | ((unsigned int)u1[j] << 16);
                *(unsigned int*)&Vt[(d0v + j)*72 + s2] = pw;   // s2 even -> 4B aligned
            }
        }
        __syncthreads();   // Ks/Vt ready

        // ---- QK^T ----
        f32x4 cs[2][4];
#pragma unroll
        for (int mt = 0; mt < 2; ++mt)
#pragma unroll
            for (int nt = 0; nt < 4; ++nt) cs[mt][nt] = (f32x4){0.f, 0.f, 0.f, 0.f};

        f16x8 aq[2][2];
#pragma unroll
        for (int mt = 0; mt < 2; ++mt)
#pragma unroll
            for (int ks = 0; ks < 2; ++ks)
                aq[mt][ks] = *(const f16x8*)&Qs[(w*32 + mt*16 + tx)*72 + ks*32 + quad*8];
#pragma unroll
        for (int nt = 0; nt < 4; ++nt) {
#pragma unroll
            for (int ks = 0; ks < 2; ++ks) {
                f16x8 bk = *(const f16x8*)&Ks[(nt*16 + tx)*72 + ks*32 + quad*8];
#pragma unroll
                for (int mt = 0; mt < 2; ++mt)
                    cs[mt][nt] = __builtin_amdgcn_mfma_f32_16x16x32_f16(aq[mt][ks], bk, cs[mt][nt], 0, 0, 0);
            }
        }

        // ---- relative-position bias (exp2 domain; rb pre-scaled by log2e) ----
        const bool farlo = (k0 - q0) >= 256;   // all rel <= -129 -> rb[0]
        const bool farhi = (q0 - k0) >= 192;   // all rel >= +129 -> rb[256]
        if (farlo | farhi) {
            const float bc = farlo ? rb[0] : rb[256];
#pragma unroll
            for (int mt = 0; mt < 2; ++mt)
#pragma unroll
                for (int nt = 0; nt < 4; ++nt)
#pragma unroll
                    for (int r = 0; r < 4; ++r) cs[mt][nt][r] += bc;
        } else {
            const int base = (q0 + w*32 + quad*4) - (k0 + tx);
#pragma unroll
            for (int mt = 0; mt < 2; ++mt)
#pragma unroll
                for (int nt = 0; nt < 4; ++nt)
#pragma unroll
                    for (int r = 0; r < 4; ++r) {
                        int rel = base + mt*16 + r - nt*16;
                        rel = rel < -128 ? -128 : (rel > 128 ? 128 : rel);
                        cs[mt][nt][r] += rb[rel + 128];
                    }
        }

        // ---- online softmax (stats per (mt,reg); cols reduce via 16-lane shfl) ----
#pragma unroll
        for (int mt = 0; mt < 2; ++mt) {
            float tm[4], mn[4], alpha[4];
#pragma unroll
            for (int r = 0; r < 4; ++r) {
                tm[r] = fmaxf(fmaxf(cs[mt][0][r], cs[mt][1][r]),
                              fmaxf(cs[mt][2][r], cs[mt][3][r]));
#pragma unroll
                for (int off = 1; off < 16; off <<= 1)
                    tm[r] = fmaxf(tm[r], __shfl_xor(tm[r], off));
                mn[r]       = fmaxf(m_run[mt][r], tm[r]);
                alpha[r]    = exp2f(m_run[mt][r] - mn[r]);
                m_run[mt][r] = mn[r];
            }
#pragma unroll
            for (int nt = 0; nt < 4; ++nt)
#pragma unroll
                for (int r = 0; r < 4; ++r)
                    cs[mt][nt][r] = exp2f(cs[mt][nt][r] - mn[r]);
#pragma unroll
            for (int r = 0; r < 4; ++r) {
                float rs = cs[mt][0][r] + cs[mt][1][r] + cs[mt][2][r] + cs[mt][3][r];
#pragma unroll
                for (int off = 1; off < 16; off <<= 1)
                    rs += __shfl_xor(rs, off);
                l_run[mt][r] = l_run[mt][r] * alpha[r] + rs;
            }
#pragma unroll
            for (int nt = 0; nt < 4; ++nt)
#pragma unroll
                for (int r = 0; r < 4; ++r) co[mt][nt][r] *= alpha[r];
            // P -> LDS (per-wave slab; C-layout scatter, f16)
#pragma unroll
            for (int nt = 0; nt < 4; ++nt)
#pragma unroll
                for (int r = 0; r < 4; ++r)
                    Ps[(w*32 + mt*16 + quad*4 + r)*72 + nt*16 + tx] = (f16)cs[mt][nt][r];
        }

        __builtin_amdgcn_wave_barrier();   // per-wave slab: order P writes before reads

        // ---- PV ----
        f16x8 ap[2][2];
#pragma unroll
        for (int mt = 0; mt < 2; ++mt)
#pragma unroll
            for (int ks = 0; ks < 2; ++ks)
                ap[mt][ks] = *(const f16x8*)&Ps[(w*32 + mt*16 + tx)*72 + ks*32 + quad*8];
#pragma unroll
        for (int nt = 0; nt < 4; ++nt) {
#pragma unroll
            for (int ks = 0; ks < 2; ++ks) {
                f16x8 bv = *(const f16x8*)&Vt[(nt*16 + tx)*72 + ks*32 + quad*8];
#pragma unroll
                for (int mt = 0; mt < 2; ++mt)
                    co[mt][nt] = __builtin_amdgcn_mfma_f32_16x16x32_f16(ap[mt][ks], bv, co[mt][nt], 0, 0, 0);
            }
        }
    }

    // ---- epilogue: normalize, write (b, s, h*64+d) ----
#pragma unroll
    for (int mt = 0; mt < 2; ++mt) {
        float inv[4];
#pragma unroll
        for (int r = 0; r < 4; ++r) inv[r] = 1.0f / l_run[mt][r];
#pragma unroll
        for (int nt = 0; nt < 4; ++nt)
#pragma unroll
            for (int r = 0; r < 4; ++r) {
                const int sg = q0 + w*32 + mt*16 + quad*4 + r;
                aout[((size_t)(b*S + sg))*DM + h*DK + nt*16 + tx] = co[mt][nt][r] * inv[r];
            }
    }
}

// ---------------------------------------------------------------------------
extern "C" void kernel_launch(void* const* d_in, const int* in_sizes, int n_in,
                              void* d_out, int out_size, void* d_ws, size_t ws_size,
                              hipStream_t stream)
{
    const float* x    = (const float*)d_in[0];
    const float* Wq   = (const float*)d_in[1];
    const float* bq   = (const float*)d_in[2];
    const float* Wk   = (const float*)d_in[3];
    const float* bk   = (const float*)d_in[4];
    const float* Wv   = (const float*)d_in[5];
    const float* bv   = (const float*)d_in[6];
    const float* Wo   = (const float*)d_in[7];
    const float* bo   = (const float*)d_in[8];
    const float* relb = (const float*)d_in[9];

    const size_t NQ = (size_t)B * NH * S * DK;   // 4,194,304 elements
    f16*   Qh = (f16*)d_ws;
    f16*   Kh = Qh + NQ;
    f16*   Vh = Kh + NQ;
    float* AO = (float*)(Vh + NQ);               // 3*NQ*2 bytes offset, 4B-aligned

    dim3 gg(DM/128, (B*S)/128);                  // (8, 32)
    gemm_xwT<true ><<<gg, 256, 0, stream>>>(x, Wq, bq, Qh, LOG2E * 0.125f);
    gemm_xwT<true ><<<gg, 256, 0, stream>>>(x, Wk, bk, Kh, 1.0f);
    gemm_xwT<true ><<<gg, 256, 0, stream>>>(x, Wv, bv, Vh, 1.0f);
    attn_f16<<<dim3(S/128, NH, B), 256, 0, stream>>>(Qh, Kh, Vh, relb, AO);
    gemm_xwT<false><<<gg, 256, 0, stream>>>(AO, Wo, bo, d_out, 1.0f);
}

// Round 3
// 284.079 us; speedup vs baseline: 4.9974x; 2.4974x over previous
//
#include <hip/hip_runtime.h>

static constexpr int DM = 1024;   // d_model
static constexpr int NH = 16;     // heads
static constexpr int DK = 64;     // head dim
static constexpr int S  = 2048;   // seq len
static constexpr int B  = 2;      // batch
static constexpr float LOG2E = 1.4426950408889634f;

typedef _Float16 f16;
typedef _Float16 f16x8 __attribute__((ext_vector_type(8)));
typedef _Float16 f16x4 __attribute__((ext_vector_type(4)));
typedef float    f32x4 __attribute__((ext_vector_type(4)));

static constexpr size_t NX = (size_t)B * S * DM;   // 4,194,304 (x elements)
static constexpr size_t NW = (size_t)DM * DM;      // 1,048,576 (per weight)

// ---------------------------------------------------------------------------
// fp32 -> f16 conversion for x and the four weight matrices (one launch).
// 8 elements per thread. Total 8M elements -> 4096 blocks x 256 threads.
// ---------------------------------------------------------------------------
__global__ __launch_bounds__(256) void cvt_f16(const float* __restrict__ x,
                                               const float* __restrict__ wq,
                                               const float* __restrict__ wk,
                                               const float* __restrict__ wv,
                                               const float* __restrict__ wo,
                                               f16* __restrict__ xh,
                                               f16* __restrict__ wqh,
                                               f16* __restrict__ wkh,
                                               f16* __restrict__ wvh,
                                               f16* __restrict__ woh)
{
    const size_t base = ((size_t)blockIdx.x * 256 + threadIdx.x) * 8;
    const float* src; f16* dst; size_t off;
    if (base < NX) { src = x; dst = xh; off = base; }
    else {
        const size_t rem = base - NX;
        const int seg = (int)(rem >> 20);          // NW = 1M = 2^20
        off = rem & (NW - 1);
        src = seg == 0 ? wq : (seg == 1 ? wk : (seg == 2 ? wv : wo));
        dst = seg == 0 ? wqh : (seg == 1 ? wkh : (seg == 2 ? wvh : woh));
    }
    float4 a = *(const float4*)&src[off];
    float4 b = *(const float4*)&src[off + 4];
    f16x8 h = { (f16)a.x, (f16)a.y, (f16)a.z, (f16)a.w,
                (f16)b.x, (f16)b.y, (f16)b.z, (f16)b.w };
    *(f16x8*)&dst[off] = h;
}

// ---------------------------------------------------------------------------
// f16 MFMA GEMM: Y = A @ W^T + bias.  A:(M,1024) f16 row-major, W:(N,1024) f16.
// 128x128 tile, BK=64, 256 threads = 4 waves, wave-tile 64x64 (4x4 MFMAs x2 ks).
// MODE 0: fused QKV — gridDim.x = 24, blockIdx.x>>3 selects {Wq,Wk,Wv};
//         epilogue: (acc+bias)*scale -> f16 scatter into (B,H,S,DK).
//         (Q pre-scale log2e/8 folded here.)
// MODE 1: out-proj — gridDim.x = 8; fp32 row-major output.
// LDS stride 72 halves: frag b128 reads <=2-way bank alias.
// ---------------------------------------------------------------------------
template<int MODE>
__global__ __launch_bounds__(256) void gemm_h(const f16* __restrict__ A,
                                              const f16* __restrict__ W0,
                                              const f16* __restrict__ W1,
                                              const f16* __restrict__ W2,
                                              const float* __restrict__ b0,
                                              const float* __restrict__ b1,
                                              const float* __restrict__ b2,
                                              void* __restrict__ o0,
                                              void* __restrict__ o1,
                                              void* __restrict__ o2)
{
    __shared__ f16 As[128 * 72];
    __shared__ f16 Bs[128 * 72];

    const int t    = threadIdx.x;
    const int w    = t >> 6;
    const int lane = t & 63;
    const int tx   = lane & 15;
    const int quad = lane >> 4;
    const int wm   = w >> 1;          // 0..1 (m half)
    const int wn   = w & 1;           // 0..1 (n half)
    const int m0   = blockIdx.y * 128;

    const f16* W; const float* bias; f16* outh = nullptr; float* outf = nullptr;
    float scale; int n0;
    if (MODE == 0) {
        const int wsel = blockIdx.x >> 3;
        n0   = (blockIdx.x & 7) * 128;
        W    = wsel == 0 ? W0 : (wsel == 1 ? W1 : W2);
        bias = wsel == 0 ? b0 : (wsel == 1 ? b1 : b2);
        outh = (f16*)(wsel == 0 ? o0 : (wsel == 1 ? o1 : o2));
        scale = wsel == 0 ? LOG2E * 0.125f : 1.0f;
    } else {
        n0 = blockIdx.x * 128;
        W = W0; bias = b0; outf = (float*)o0; scale = 1.0f;
    }

    // staging assignment: thread t covers rows (t>>2, t>>2 + 64), k-chunks
    // (t&3)*8 and (t&3)*8+32 halves -> 4 f16x8 per tile per step.
    const int lr = t >> 2;
    const int lc = (t & 3) * 8;

    f32x4 acc[4][4];
#pragma unroll
    for (int mt = 0; mt < 4; ++mt)
#pragma unroll
        for (int nt = 0; nt < 4; ++nt) acc[mt][nt] = (f32x4){0.f, 0.f, 0.f, 0.f};

    f16x8 ga[4], gb[4];
    {   // prefetch k0 = 0
        const f16* Ap = A + (size_t)(m0 + lr) * DM + lc;
        const f16* Wp = W + (size_t)(n0 + lr) * DM + lc;
        ga[0] = *(const f16x8*)(Ap);
        ga[1] = *(const f16x8*)(Ap + 32);
        ga[2] = *(const f16x8*)(Ap + (size_t)64 * DM);
        ga[3] = *(const f16x8*)(Ap + (size_t)64 * DM + 32);
        gb[0] = *(const f16x8*)(Wp);
        gb[1] = *(const f16x8*)(Wp + 32);
        gb[2] = *(const f16x8*)(Wp + (size_t)64 * DM);
        gb[3] = *(const f16x8*)(Wp + (size_t)64 * DM + 32);
    }

    for (int k0 = 0; k0 < DM; k0 += 64) {
        __syncthreads();   // previous compute done before overwrite
        *(f16x8*)&As[ lr       * 72 + lc     ] = ga[0];
        *(f16x8*)&As[ lr       * 72 + lc + 32] = ga[1];
        *(f16x8*)&As[(lr + 64) * 72 + lc     ] = ga[2];
        *(f16x8*)&As[(lr + 64) * 72 + lc + 32] = ga[3];
        *(f16x8*)&Bs[ lr       * 72 + lc     ] = gb[0];
        *(f16x8*)&Bs[ lr       * 72 + lc + 32] = gb[1];
        *(f16x8*)&Bs[(lr + 64) * 72 + lc     ] = gb[2];
        *(f16x8*)&Bs[(lr + 64) * 72 + lc + 32] = gb[3];
        if (k0 + 64 < DM) {   // prefetch next step (latency hidden by compute)
            const f16* Ap = A + (size_t)(m0 + lr) * DM + k0 + 64 + lc;
            const f16* Wp = W + (size_t)(n0 + lr) * DM + k0 + 64 + lc;
            ga[0] = *(const f16x8*)(Ap);
            ga[1] = *(const f16x8*)(Ap + 32);
            ga[2] = *(const f16x8*)(Ap + (size_t)64 * DM);
            ga[3] = *(const f16x8*)(Ap + (size_t)64 * DM + 32);
            gb[0] = *(const f16x8*)(Wp);
            gb[1] = *(const f16x8*)(Wp + 32);
            gb[2] = *(const f16x8*)(Wp + (size_t)64 * DM);
            gb[3] = *(const f16x8*)(Wp + (size_t)64 * DM + 32);
        }
        __syncthreads();   // tiles ready

        f16x8 af[4][2];
#pragma unroll
        for (int mt = 0; mt < 4; ++mt)
#pragma unroll
            for (int ks = 0; ks < 2; ++ks)
                af[mt][ks] = *(const f16x8*)&As[(wm*64 + mt*16 + tx)*72 + ks*32 + quad*8];
#pragma unroll
        for (int nt = 0; nt < 4; ++nt) {
#pragma unroll
            for (int ks = 0; ks < 2; ++ks) {
                f16x8 bf = *(const f16x8*)&Bs[(wn*64 + nt*16 + tx)*72 + ks*32 + quad*8];
#pragma unroll
                for (int mt = 0; mt < 4; ++mt)
                    acc[mt][nt] = __builtin_amdgcn_mfma_f32_16x16x32_f16(af[mt][ks], bf, acc[mt][nt], 0, 0, 0);
            }
        }
    }

    // epilogue
#pragma unroll
    for (int nt = 0; nt < 4; ++nt) {
        const int n = n0 + wn*64 + nt*16 + tx;
        const float bn = bias[n];
#pragma unroll
        for (int mt = 0; mt < 4; ++mt)
#pragma unroll
            for (int r = 0; r < 4; ++r) {
                const int m = m0 + wm*64 + mt*16 + quad*4 + r;
                const float v = (acc[mt][nt][r] + bn) * scale;
                if (MODE == 0) {
                    const int bi = m >> 11;
                    const int ss = m & (S - 1);
                    const int h  = n >> 6;
                    const int dk = n & (DK - 1);
                    outh[((size_t)((bi*NH + h)*S + ss))*DK + dk] = (f16)v;
                } else {
                    outf[(size_t)m * DM + n] = v;
                }
            }
    }
}

// ---------------------------------------------------------------------------
// Flash attention, f16 MFMA core (unchanged from round 2 except f16 output).
// ---------------------------------------------------------------------------
__global__ __launch_bounds__(256) void attn_f16(const f16* __restrict__ Q,
                                                const f16* __restrict__ K,
                                                const f16* __restrict__ V,
                                                const float* __restrict__ relb,
                                                f16* __restrict__ aout)
{
    __shared__ f16 Qs[128*72];
    __shared__ f16 Ks[64*72];
    __shared__ f16 Vt[64*72];     // transposed: Vt[d][seq]
    __shared__ f16 Ps[128*72];    // per-wave 32-row slabs
    __shared__ float rb[257];

    const int t    = threadIdx.x;
    const int w    = t >> 6;
    const int lane = t & 63;
    const int tx   = lane & 15;
    const int quad = lane >> 4;
    const int q0   = blockIdx.x * 128;
    const int h    = blockIdx.y;
    const int b    = blockIdx.z;

    const f16* Qb = Q + (size_t)((b*NH + h) * S) * DK;
    const f16* Kb = K + (size_t)((b*NH + h) * S) * DK;
    const f16* Vb = V + (size_t)((b*NH + h) * S) * DK;

    for (int i = t; i < 257; i += 256) rb[i] = relb[h*257 + i] * LOG2E;

    {   // stage Q once (already pre-scaled by log2e/8 in GEMM epilogue)
        const int row = t >> 1;
        const int ch  = (t & 1) * 32;
        const f16* src = Qb + (size_t)(q0 + row) * DK + ch;
#pragma unroll
        for (int j = 0; j < 4; ++j)
            *(f16x8*)&Qs[row*72 + ch + j*8] = *(const f16x8*)(src + j*8);
    }

    f32x4 co[2][4];
    float m_run[2][4], l_run[2][4];
#pragma unroll
    for (int mt = 0; mt < 2; ++mt)
#pragma unroll
        for (int r = 0; r < 4; ++r) { m_run[mt][r] = -1e30f; l_run[mt][r] = 0.f; }
#pragma unroll
    for (int mt = 0; mt < 2; ++mt)
#pragma unroll
        for (int nt = 0; nt < 4; ++nt) co[mt][nt] = (f32x4){0.f, 0.f, 0.f, 0.f};

    for (int kt = 0; kt < S/64; ++kt) {
        const int k0 = kt * 64;

        const int seq = t & 63, d0k = (t >> 6) * 16;
        f16x8 kr0 = *(const f16x8*)(Kb + (size_t)(k0 + seq)*DK + d0k);
        f16x8 kr1 = *(const f16x8*)(Kb + (size_t)(k0 + seq)*DK + d0k + 8);
        const int s2 = (t & 31) * 2, d0v = (t >> 5) * 8;
        f16x8 vr0 = *(const f16x8*)(Vb + (size_t)(k0 + s2    )*DK + d0v);
        f16x8 vr1 = *(const f16x8*)(Vb + (size_t)(k0 + s2 + 1)*DK + d0v);

        __syncthreads();
        *(f16x8*)&Ks[seq*72 + d0k    ] = kr0;
        *(f16x8*)&Ks[seq*72 + d0k + 8] = kr1;
        {
            const unsigned short* u0 = (const unsigned short*)&vr0;
            const unsigned short* u1 = (const unsigned short*)&vr1;
#pragma unroll
            for (int j = 0; j < 8; ++j) {
                unsigned int pw = (unsigned int)u0[j] | ((unsigned int)u1[j] << 16);
                *(unsigned int*)&Vt[(d0v + j)*72 + s2] = pw;
            }
        }
        __syncthreads();

        // ---- QK^T ----
        f32x4 cs[2][4];
#pragma unroll
        for (int mt = 0; mt < 2; ++mt)
#pragma unroll
            for (int nt = 0; nt < 4; ++nt) cs[mt][nt] = (f32x4){0.f, 0.f, 0.f, 0.f};

        f16x8 aq[2][2];
#pragma unroll
        for (int mt = 0; mt < 2; ++mt)
#pragma unroll
            for (int ks = 0; ks < 2; ++ks)
                aq[mt][ks] = *(const f16x8*)&Qs[(w*32 + mt*16 + tx)*72 + ks*32 + quad*8];
#pragma unroll
        for (int nt = 0; nt < 4; ++nt) {
#pragma unroll
            for (int ks = 0; ks < 2; ++ks) {
                f16x8 bk = *(const f16x8*)&Ks[(nt*16 + tx)*72 + ks*32 + quad*8];
#pragma unroll
                for (int mt = 0; mt < 2; ++mt)
                    cs[mt][nt] = __builtin_amdgcn_mfma_f32_16x16x32_f16(aq[mt][ks], bk, cs[mt][nt], 0, 0, 0);
            }
        }

        // ---- relative bias ----
        const bool farlo = (k0 - q0) >= 256;
        const bool farhi = (q0 - k0) >= 192;
        if (farlo | farhi) {
            const float bc = farlo ? rb[0] : rb[256];
#pragma unroll
            for (int mt = 0; mt < 2; ++mt)
#pragma unroll
                for (int nt = 0; nt < 4; ++nt)
#pragma unroll
                    for (int r = 0; r < 4; ++r) cs[mt][nt][r] += bc;
        } else {
            const int base = (q0 + w*32 + quad*4) - (k0 + tx);
#pragma unroll
            for (int mt = 0; mt < 2; ++mt)
#pragma unroll
                for (int nt = 0; nt < 4; ++nt)
#pragma unroll
                    for (int r = 0; r < 4; ++r) {
                        int rel = base + mt*16 + r - nt*16;
                        rel = rel < -128 ? -128 : (rel > 128 ? 128 : rel);
                        cs[mt][nt][r] += rb[rel + 128];
                    }
        }

        // ---- online softmax ----
#pragma unroll
        for (int mt = 0; mt < 2; ++mt) {
            float tm[4], mn[4], alpha[4];
#pragma unroll
            for (int r = 0; r < 4; ++r) {
                tm[r] = fmaxf(fmaxf(cs[mt][0][r], cs[mt][1][r]),
                              fmaxf(cs[mt][2][r], cs[mt][3][r]));
#pragma unroll
                for (int off = 1; off < 16; off <<= 1)
                    tm[r] = fmaxf(tm[r], __shfl_xor(tm[r], off));
                mn[r]        = fmaxf(m_run[mt][r], tm[r]);
                alpha[r]     = exp2f(m_run[mt][r] - mn[r]);
                m_run[mt][r] = mn[r];
            }
#pragma unroll
            for (int nt = 0; nt < 4; ++nt)
#pragma unroll
                for (int r = 0; r < 4; ++r)
                    cs[mt][nt][r] = exp2f(cs[mt][nt][r] - mn[r]);
#pragma unroll
            for (int r = 0; r < 4; ++r) {
                float rs = cs[mt][0][r] + cs[mt][1][r] + cs[mt][2][r] + cs[mt][3][r];
#pragma unroll
                for (int off = 1; off < 16; off <<= 1)
                    rs += __shfl_xor(rs, off);
                l_run[mt][r] = l_run[mt][r] * alpha[r] + rs;
            }
#pragma unroll
            for (int nt = 0; nt < 4; ++nt)
#pragma unroll
                for (int r = 0; r < 4; ++r) co[mt][nt][r] *= alpha[r];
#pragma unroll
            for (int nt = 0; nt < 4; ++nt)
#pragma unroll
                for (int r = 0; r < 4; ++r)
                    Ps[(w*32 + mt*16 + quad*4 + r)*72 + nt*16 + tx] = (f16)cs[mt][nt][r];
        }

        __builtin_amdgcn_wave_barrier();

        // ---- PV ----
        f16x8 ap[2][2];
#pragma unroll
        for (int mt = 0; mt < 2; ++mt)
#pragma unroll
            for (int ks = 0; ks < 2; ++ks)
                ap[mt][ks] = *(const f16x8*)&Ps[(w*32 + mt*16 + tx)*72 + ks*32 + quad*8];
#pragma unroll
        for (int nt = 0; nt < 4; ++nt) {
#pragma unroll
            for (int ks = 0; ks < 2; ++ks) {
                f16x8 bv = *(const f16x8*)&Vt[(nt*16 + tx)*72 + ks*32 + quad*8];
#pragma unroll
                for (int mt = 0; mt < 2; ++mt)
                    co[mt][nt] = __builtin_amdgcn_mfma_f32_16x16x32_f16(ap[mt][ks], bv, co[mt][nt], 0, 0, 0);
            }
        }
    }

    // ---- epilogue: normalize, write f16 (b, s, h*64+d) ----
#pragma unroll
    for (int mt = 0; mt < 2; ++mt) {
        float inv[4];
#pragma unroll
        for (int r = 0; r < 4; ++r) inv[r] = 1.0f / l_run[mt][r];
#pragma unroll
        for (int nt = 0; nt < 4; ++nt)
#pragma unroll
            for (int r = 0; r < 4; ++r) {
                const int sg = q0 + w*32 + mt*16 + quad*4 + r;
                aout[((size_t)(b*S + sg))*DM + h*DK + nt*16 + tx] = (f16)(co[mt][nt][r] * inv[r]);
            }
    }
}

// ---------------------------------------------------------------------------
extern "C" void kernel_launch(void* const* d_in, const int* in_sizes, int n_in,
                              void* d_out, int out_size, void* d_ws, size_t ws_size,
                              hipStream_t stream)
{
    const float* x    = (const float*)d_in[0];
    const float* Wq   = (const float*)d_in[1];
    const float* bq   = (const float*)d_in[2];
    const float* Wk   = (const float*)d_in[3];
    const float* bk   = (const float*)d_in[4];
    const float* Wv   = (const float*)d_in[5];
    const float* bv   = (const float*)d_in[6];
    const float* Wo   = (const float*)d_in[7];
    const float* bo   = (const float*)d_in[8];
    const float* relb = (const float*)d_in[9];

    f16* Xh  = (f16*)d_ws;          // 4M halves
    f16* Wqh = Xh  + NX;            // 1M each
    f16* Wkh = Wqh + NW;
    f16* Wvh = Wkh + NW;
    f16* Woh = Wvh + NW;
    f16* Qh  = Woh + NW;            // 4M each, (B,H,S,DK)
    f16* Kh  = Qh  + NX;
    f16* Vh  = Kh  + NX;
    f16* AOh = Vh  + NX;            // 4M, (B*S, DM)

    cvt_f16<<<(NX + 4*NW) / (256*8), 256, 0, stream>>>(x, Wq, Wk, Wv, Wo,
                                                       Xh, Wqh, Wkh, Wvh, Woh);
    gemm_h<0><<<dim3(24, 32), 256, 0, stream>>>(Xh, Wqh, Wkh, Wvh,
                                                bq, bk, bv, Qh, Kh, Vh);
    attn_f16<<<dim3(S/128, NH, B), 256, 0, stream>>>(Qh, Kh, Vh, relb, AOh);
    gemm_h<1><<<dim3(8, 32), 256, 0, stream>>>(AOh, Woh, nullptr, nullptr,
                                               bo, nullptr, nullptr,
                                               d_out, nullptr, nullptr);
}

// Round 4
// 219.998 us; speedup vs baseline: 6.4530x; 1.2913x over previous
//
#include <hip/hip_runtime.h>

static constexpr int DM = 1024;   // d_model
static constexpr int NH = 16;     // heads
static constexpr int DK = 64;     // head dim
static constexpr int S  = 2048;   // seq len
static constexpr int B  = 2;      // batch
static constexpr float LOG2E = 1.4426950408889634f;
static constexpr float FMAX  = 11.0f;   // fixed softmax shift (exp2 domain)

typedef _Float16 f16;
typedef _Float16 f16x8 __attribute__((ext_vector_type(8)));
typedef _Float16 f16x4 __attribute__((ext_vector_type(4)));
typedef float    f32x4 __attribute__((ext_vector_type(4)));

static constexpr size_t NX = (size_t)B * S * DM;   // 4,194,304
static constexpr size_t NW = (size_t)DM * DM;      // 1,048,576

// ---------------------------------------------------------------------------
// fp32 -> f16 conversion for x and the four weight matrices (one launch).
// ---------------------------------------------------------------------------
__global__ __launch_bounds__(256) void cvt_f16(const float* __restrict__ x,
                                               const float* __restrict__ wq,
                                               const float* __restrict__ wk,
                                               const float* __restrict__ wv,
                                               const float* __restrict__ wo,
                                               f16* __restrict__ xh,
                                               f16* __restrict__ wqh,
                                               f16* __restrict__ wkh,
                                               f16* __restrict__ wvh,
                                               f16* __restrict__ woh)
{
    const size_t base = ((size_t)blockIdx.x * 256 + threadIdx.x) * 8;
    const float* src; f16* dst; size_t off;
    if (base < NX) { src = x; dst = xh; off = base; }
    else {
        const size_t rem = base - NX;
        const int seg = (int)(rem >> 20);
        off = rem & (NW - 1);
        src = seg == 0 ? wq : (seg == 1 ? wk : (seg == 2 ? wv : wo));
        dst = seg == 0 ? wqh : (seg == 1 ? wkh : (seg == 2 ? wvh : woh));
    }
    float4 a = *(const float4*)&src[off];
    float4 b = *(const float4*)&src[off + 4];
    f16x8 h = { (f16)a.x, (f16)a.y, (f16)a.z, (f16)a.w,
                (f16)b.x, (f16)b.y, (f16)b.z, (f16)b.w };
    *(f16x8*)&dst[off] = h;
}

// ---------------------------------------------------------------------------
// f16 MFMA GEMM (unchanged from round 3).
// ---------------------------------------------------------------------------
template<int MODE>
__global__ __launch_bounds__(256) void gemm_h(const f16* __restrict__ A,
                                              const f16* __restrict__ W0,
                                              const f16* __restrict__ W1,
                                              const f16* __restrict__ W2,
                                              const float* __restrict__ b0,
                                              const float* __restrict__ b1,
                                              const float* __restrict__ b2,
                                              void* __restrict__ o0,
                                              void* __restrict__ o1,
                                              void* __restrict__ o2)
{
    __shared__ f16 As[128 * 72];
    __shared__ f16 Bs[128 * 72];

    const int t    = threadIdx.x;
    const int w    = t >> 6;
    const int lane = t & 63;
    const int tx   = lane & 15;
    const int quad = lane >> 4;
    const int wm   = w >> 1;
    const int wn   = w & 1;
    const int m0   = blockIdx.y * 128;

    const f16* W; const float* bias; f16* outh = nullptr; float* outf = nullptr;
    float scale; int n0;
    if (MODE == 0) {
        const int wsel = blockIdx.x >> 3;
        n0   = (blockIdx.x & 7) * 128;
        W    = wsel == 0 ? W0 : (wsel == 1 ? W1 : W2);
        bias = wsel == 0 ? b0 : (wsel == 1 ? b1 : b2);
        outh = (f16*)(wsel == 0 ? o0 : (wsel == 1 ? o1 : o2));
        scale = wsel == 0 ? LOG2E * 0.125f : 1.0f;
    } else {
        n0 = blockIdx.x * 128;
        W = W0; bias = b0; outf = (float*)o0; scale = 1.0f;
    }

    const int lr = t >> 2;
    const int lc = (t & 3) * 8;

    f32x4 acc[4][4];
#pragma unroll
    for (int mt = 0; mt < 4; ++mt)
#pragma unroll
        for (int nt = 0; nt < 4; ++nt) acc[mt][nt] = (f32x4){0.f, 0.f, 0.f, 0.f};

    f16x8 ga[4], gb[4];
    {
        const f16* Ap = A + (size_t)(m0 + lr) * DM + lc;
        const f16* Wp = W + (size_t)(n0 + lr) * DM + lc;
        ga[0] = *(const f16x8*)(Ap);
        ga[1] = *(const f16x8*)(Ap + 32);
        ga[2] = *(const f16x8*)(Ap + (size_t)64 * DM);
        ga[3] = *(const f16x8*)(Ap + (size_t)64 * DM + 32);
        gb[0] = *(const f16x8*)(Wp);
        gb[1] = *(const f16x8*)(Wp + 32);
        gb[2] = *(const f16x8*)(Wp + (size_t)64 * DM);
        gb[3] = *(const f16x8*)(Wp + (size_t)64 * DM + 32);
    }

    for (int k0 = 0; k0 < DM; k0 += 64) {
        __syncthreads();
        *(f16x8*)&As[ lr       * 72 + lc     ] = ga[0];
        *(f16x8*)&As[ lr       * 72 + lc + 32] = ga[1];
        *(f16x8*)&As[(lr + 64) * 72 + lc     ] = ga[2];
        *(f16x8*)&As[(lr + 64) * 72 + lc + 32] = ga[3];
        *(f16x8*)&Bs[ lr       * 72 + lc     ] = gb[0];
        *(f16x8*)&Bs[ lr       * 72 + lc + 32] = gb[1];
        *(f16x8*)&Bs[(lr + 64) * 72 + lc     ] = gb[2];
        *(f16x8*)&Bs[(lr + 64) * 72 + lc + 32] = gb[3];
        if (k0 + 64 < DM) {
            const f16* Ap = A + (size_t)(m0 + lr) * DM + k0 + 64 + lc;
            const f16* Wp = W + (size_t)(n0 + lr) * DM + k0 + 64 + lc;
            ga[0] = *(const f16x8*)(Ap);
            ga[1] = *(const f16x8*)(Ap + 32);
            ga[2] = *(const f16x8*)(Ap + (size_t)64 * DM);
            ga[3] = *(const f16x8*)(Ap + (size_t)64 * DM + 32);
            gb[0] = *(const f16x8*)(Wp);
            gb[1] = *(const f16x8*)(Wp + 32);
            gb[2] = *(const f16x8*)(Wp + (size_t)64 * DM);
            gb[3] = *(const f16x8*)(Wp + (size_t)64 * DM + 32);
        }
        __syncthreads();

        f16x8 af[4][2];
#pragma unroll
        for (int mt = 0; mt < 4; ++mt)
#pragma unroll
            for (int ks = 0; ks < 2; ++ks)
                af[mt][ks] = *(const f16x8*)&As[(wm*64 + mt*16 + tx)*72 + ks*32 + quad*8];
#pragma unroll
        for (int nt = 0; nt < 4; ++nt) {
#pragma unroll
            for (int ks = 0; ks < 2; ++ks) {
                f16x8 bf = *(const f16x8*)&Bs[(wn*64 + nt*16 + tx)*72 + ks*32 + quad*8];
#pragma unroll
                for (int mt = 0; mt < 4; ++mt)
                    acc[mt][nt] = __builtin_amdgcn_mfma_f32_16x16x32_f16(af[mt][ks], bf, acc[mt][nt], 0, 0, 0);
            }
        }
    }

#pragma unroll
    for (int nt = 0; nt < 4; ++nt) {
        const int n = n0 + wn*64 + nt*16 + tx;
        const float bn = bias[n];
#pragma unroll
        for (int mt = 0; mt < 4; ++mt)
#pragma unroll
            for (int r = 0; r < 4; ++r) {
                const int m = m0 + wm*64 + mt*16 + quad*4 + r;
                const float v = (acc[mt][nt][r] + bn) * scale;
                if (MODE == 0) {
                    const int bi = m >> 11;
                    const int ss = m & (S - 1);
                    const int h  = n >> 6;
                    const int dk = n & (DK - 1);
                    outh[((size_t)((bi*NH + h)*S + ss))*DK + dk] = (f16)v;
                } else {
                    outf[(size_t)m * DM + n] = v;
                }
            }
    }
}

// ---------------------------------------------------------------------------
// Flash attention v3: S^T trick + fixed-max softmax + 2-way seq split.
// Block = (q-tile of 128, split sp of 16 k-tiles); 256 threads = 4 waves,
// wave handles 32 q (2 x 16-col blocks).
//   QK: A=K, B=Q -> S^T C-layout (row=s, col=q). P^T regs == B-operand layout
//   of mfma_f32_16x16x16f16 -> PV needs NO LDS round trip.
//   PV: A=V^T (quad-grouped LDS layout, b128 = 2 k-chunk frags), B=P^T
//       -> O^T C-layout (row=d contiguous per reg -> b128 stores).
// Outputs: Onum f32 partial numerator, lpart partial denominators; tiny
// combine kernel merges the 2 splits (fixed-max partials just add).
// ---------------------------------------------------------------------------
__global__ __launch_bounds__(256, 4) void attn_v3(const f16* __restrict__ Q,
                                                  const f16* __restrict__ K,
                                                  const f16* __restrict__ V,
                                                  const float* __restrict__ relb,
                                                  float* __restrict__ On,
                                                  float* __restrict__ lp)
{
    __shared__ f16 Ks[64*72];
    __shared__ f16 Vt[64*72];    // quad-grouped V^T: addr(d,s)=d*72+g(s)
    __shared__ float rb2[257];

    const int t    = threadIdx.x;
    const int w    = t >> 6;
    const int lane = t & 63;
    const int tx   = lane & 15;
    const int quad = lane >> 4;
    const int qt   = blockIdx.x >> 1;
    const int sp   = blockIdx.x & 1;
    const int h    = blockIdx.y;
    const int b    = blockIdx.z;
    const int q0   = qt * 128;

    const f16* Qb = Q + (size_t)((b*NH + h) * S) * DK;
    const f16* Kb = K + (size_t)((b*NH + h) * S) * DK;
    const f16* Vb = V + (size_t)((b*NH + h) * S) * DK;

    for (int i = t; i < 257; i += 256) rb2[i] = relb[h*257 + i] * LOG2E - FMAX;

    // Q fragments straight from global (one-time; B-operand layout: n=q, k=d)
    const int qrow = q0 + w*32 + tx;
    f16x8 qf[2][2];
#pragma unroll
    for (int qb = 0; qb < 2; ++qb)
#pragma unroll
        for (int ks = 0; ks < 2; ++ks)
            qf[qb][ks] = *(const f16x8*)(Qb + (size_t)(qrow + qb*16)*DK + ks*32 + quad*8);

    f32x4 oT[4][2];               // O^T accum [dblk][qblk]
    float lsum[2] = {0.f, 0.f};
#pragma unroll
    for (int d = 0; d < 4; ++d)
#pragma unroll
        for (int qb = 0; qb < 2; ++qb) oT[d][qb] = (f32x4){0.f, 0.f, 0.f, 0.f};

    const int kt0 = sp * (S/128);        // 16 tiles per split
    for (int kt = kt0; kt < kt0 + S/128; ++kt) {
        const int k0 = kt * 64;

        // ---- global prefetch ----
        const int seq = t & 63, d0k = (t >> 6) * 16;
        f16x8 kr0 = *(const f16x8*)(Kb + (size_t)(k0 + seq)*DK + d0k);
        f16x8 kr1 = *(const f16x8*)(Kb + (size_t)(k0 + seq)*DK + d0k + 8);
        const int s2 = (t & 31) * 2, d0v = (t >> 5) * 8;
        f16x8 vr0 = *(const f16x8*)(Vb + (size_t)(k0 + s2    )*DK + d0v);
        f16x8 vr1 = *(const f16x8*)(Vb + (size_t)(k0 + s2 + 1)*DK + d0v);

        __syncthreads();   // previous tile consumed (also covers rb2 on iter 0)
        *(f16x8*)&Ks[seq*72 + d0k    ] = kr0;
        *(f16x8*)&Ks[seq*72 + d0k + 8] = kr1;
        {   // V^T quad-grouped: g(s) = ((s>>2)&3)*16 + (s>>4)*4 + (s&3)
            const int g = ((s2 >> 2) & 3)*16 + (s2 >> 4)*4 + (s2 & 3);
            const unsigned short* u0 = (const unsigned short*)&vr0;
            const unsigned short* u1 = (const unsigned short*)&vr1;
#pragma unroll
            for (int j = 0; j < 8; ++j) {
                unsigned int pw = (unsigned int)u0[j] | ((unsigned int)u1[j] << 16);
                *(unsigned int*)&Vt[(d0v + j)*72 + g] = pw;
            }
        }
        __syncthreads();

        const bool farlo = (k0 - q0) >= 256;
        const bool farhi = (q0 - k0) >= 192;
        const float bconst = farlo ? rb2[0] : rb2[256];
        const int relbase = (q0 + w*32 + tx) - (k0 + quad*4);

        // ---- QK^T (S^T) + softmax, per 16-s block ----
        f16x4 pf[4][2];
#pragma unroll
        for (int sb = 0; sb < 4; ++sb) {
            f32x4 sT[2] = {(f32x4){0.f,0.f,0.f,0.f}, (f32x4){0.f,0.f,0.f,0.f}};
#pragma unroll
            for (int ks = 0; ks < 2; ++ks) {
                f16x8 kf = *(const f16x8*)&Ks[(sb*16 + tx)*72 + ks*32 + quad*8];
#pragma unroll
                for (int qb = 0; qb < 2; ++qb)
                    sT[qb] = __builtin_amdgcn_mfma_f32_16x16x32_f16(kf, qf[qb][ks], sT[qb], 0, 0, 0);
            }
            if (farlo | farhi) {
#pragma unroll
                for (int qb = 0; qb < 2; ++qb)
#pragma unroll
                    for (int r = 0; r < 4; ++r) {
                        const float p = exp2f(sT[qb][r] + bconst);
                        lsum[qb] += p;
                        pf[sb][qb][r] = (f16)p;
                    }
            } else {
#pragma unroll
                for (int qb = 0; qb < 2; ++qb)
#pragma unroll
                    for (int r = 0; r < 4; ++r) {
                        int rel = relbase + qb*16 - sb*16 - r;
                        rel = rel < -128 ? -128 : (rel > 128 ? 128 : rel);
                        const float p = exp2f(sT[qb][r] + rb2[rel + 128]);
                        lsum[qb] += p;
                        pf[sb][qb][r] = (f16)p;
                    }
            }
        }

        // ---- PV: O^T += V^T · P^T (P frags direct from registers) ----
#pragma unroll
        for (int d = 0; d < 4; ++d) {
#pragma unroll
            for (int sp2 = 0; sp2 < 2; ++sp2) {
                f16x8 vv = *(const f16x8*)&Vt[(d*16 + tx)*72 + quad*16 + sp2*8];
                f16x4 vlo = __builtin_shufflevector(vv, vv, 0, 1, 2, 3);
                f16x4 vhi = __builtin_shufflevector(vv, vv, 4, 5, 6, 7);
#pragma unroll
                for (int qb = 0; qb < 2; ++qb) {
                    oT[d][qb] = __builtin_amdgcn_mfma_f32_16x16x16f16(vlo, pf[sp2*2    ][qb], oT[d][qb], 0, 0, 0);
                    oT[d][qb] = __builtin_amdgcn_mfma_f32_16x16x16f16(vhi, pf[sp2*2 + 1][qb], oT[d][qb], 0, 0, 0);
                }
            }
        }
    }

    // ---- epilogue: partial numerator (f32) + partial denominator ----
#pragma unroll
    for (int qb = 0; qb < 2; ++qb) {
        float l = lsum[qb];
        l += __shfl_xor(l, 16);
        l += __shfl_xor(l, 32);
        const int q = q0 + w*32 + qb*16 + tx;
        if (quad == 0)
            lp[(((size_t)sp*B + b)*NH + h)*S + q] = l;
#pragma unroll
        for (int d = 0; d < 4; ++d)
            *(f32x4*)&On[(size_t)sp*NX + ((size_t)(b*S + q))*DM + h*DK + d*16 + quad*4] = oT[d][qb];
    }
}

// ---------------------------------------------------------------------------
// Combine the two seq-splits: AOh = (On0 + On1) / (l0 + l1), f16 output.
// ---------------------------------------------------------------------------
__global__ __launch_bounds__(256) void combine(const float* __restrict__ On,
                                               const float* __restrict__ lp,
                                               f16* __restrict__ AOh)
{
    const size_t i8 = ((size_t)blockIdx.x * 256 + threadIdx.x) * 8;
    const int token = (int)(i8 >> 10);
    const int c     = (int)(i8 & (DM - 1));
    const int b     = token >> 11;
    const int st    = token & (S - 1);
    const int h     = c >> 6;
    const float l = lp[((size_t)b*NH + h)*S + st]
                  + lp[(((size_t)B + b)*NH + h)*S + st];
    const float inv = 1.0f / l;
    float4 a0 = *(const float4*)&On[i8];
    float4 a1 = *(const float4*)&On[i8 + 4];
    float4 b0 = *(const float4*)&On[NX + i8];
    float4 b1 = *(const float4*)&On[NX + i8 + 4];
    f16x8 o = { (f16)((a0.x + b0.x) * inv), (f16)((a0.y + b0.y) * inv),
                (f16)((a0.z + b0.z) * inv), (f16)((a0.w + b0.w) * inv),
                (f16)((a1.x + b1.x) * inv), (f16)((a1.y + b1.y) * inv),
                (f16)((a1.z + b1.z) * inv), (f16)((a1.w + b1.w) * inv) };
    *(f16x8*)&AOh[i8] = o;
}

// ---------------------------------------------------------------------------
extern "C" void kernel_launch(void* const* d_in, const int* in_sizes, int n_in,
                              void* d_out, int out_size, void* d_ws, size_t ws_size,
                              hipStream_t stream)
{
    const float* x    = (const float*)d_in[0];
    const float* Wq   = (const float*)d_in[1];
    const float* bq   = (const float*)d_in[2];
    const float* Wk   = (const float*)d_in[3];
    const float* bk   = (const float*)d_in[4];
    const float* Wv   = (const float*)d_in[5];
    const float* bv   = (const float*)d_in[6];
    const float* Wo   = (const float*)d_in[7];
    const float* bo   = (const float*)d_in[8];
    const float* relb = (const float*)d_in[9];

    f16* Xh  = (f16*)d_ws;
    f16* Wqh = Xh  + NX;
    f16* Wkh = Wqh + NW;
    f16* Wvh = Wkh + NW;
    f16* Woh = Wvh + NW;
    f16* Qh  = Woh + NW;
    f16* Kh  = Qh  + NX;
    f16* Vh  = Kh  + NX;
    f16* AOh = Vh  + NX;
    float* On = (float*)(AOh + NX);       // 2*NX floats
    float* lpart = On + 2*NX;             // 2*B*NH*S floats

    cvt_f16<<<(NX + 4*NW) / (256*8), 256, 0, stream>>>(x, Wq, Wk, Wv, Wo,
                                                       Xh, Wqh, Wkh, Wvh, Woh);
    gemm_h<0><<<dim3(24, 32), 256, 0, stream>>>(Xh, Wqh, Wkh, Wvh,
                                                bq, bk, bv, Qh, Kh, Vh);
    attn_v3<<<dim3((S/128)*2, NH, B), 256, 0, stream>>>(Qh, Kh, Vh, relb, On, lpart);
    combine<<<NX / (256*8), 256, 0, stream>>>(On, lpart, AOh);
    gemm_h<1><<<dim3(8, 32), 256, 0, stream>>>(AOh, Woh, nullptr, nullptr,
                                               bo, nullptr, nullptr,
                                               d_out, nullptr, nullptr);
}